// Round 13
// baseline (11978.056 us; speedup 1.0000x reference)
//
#include <hip/hip_runtime.h>
#include <hip/hip_bf16.h>

#define T_LEN 512
#define NB 64      // batch
#define FB 256     // input features
#define SB 1024    // hidden size
#define NWG 256    // persistent single-wave workgroups

typedef __attribute__((ext_vector_type(8))) short bf16x8;
typedef __attribute__((ext_vector_type(4))) float f32x4;

#define MFMA(a, b, c) __builtin_amdgcn_mfma_f32_16x16x32_bf16((a), (b), (c), 0, 0, 0)

// device-scope (sc1) 16B fragment load as 2 relaxed agent u64 atomics
__device__ __forceinline__ bf16x8 load_frag_dev(const __hip_bfloat16* p) {
    const unsigned long long* q = (const unsigned long long*)p;
    unsigned long long a = __hip_atomic_load(q,     __ATOMIC_RELAXED, __HIP_MEMORY_SCOPE_AGENT);
    unsigned long long b = __hip_atomic_load(q + 1, __ATOMIC_RELAXED, __HIP_MEMORY_SCOPE_AGENT);
    union { unsigned long long u[2]; bf16x8 v; } r;
    r.u[0] = a; r.u[1] = b;
    return r.v;
}

// ---------------- prep: x -> MFMA A-fragment order, bf16 ----------------
// XAf[t][m(4)][kc(8)][lane*8+e] ; element = x[t][m*16+(l&15)][kc*32+8*(l>>4)+e]
__global__ void xfrag_kernel(const float* __restrict__ x, __hip_bfloat16* __restrict__ xaf) {
    int tid  = blockIdx.x * 256 + threadIdx.x;   // total T*4*8*64 = 1,048,576
    int l    = tid & 63;
    int frag = tid >> 6;                         // t*32 + m*8 + kc
    int kc   = frag & 7;
    int m    = (frag >> 3) & 3;
    int t    = frag >> 5;
    int row  = m * 16 + (l & 15);
    int k0   = kc * 32 + 8 * (l >> 4);
    const float* src = x + ((size_t)(t * NB + row)) * FB + k0;
    __hip_bfloat16* dst = xaf + (size_t)frag * 512 + l * 8;
#pragma unroll
    for (int e = 0; e < 8; ++e) dst[e] = __float2bfloat16(src[e]);
}

// ------------- prep: [Wx;Wh] -> per-sb contiguous stream order -------------
// WBf[sb(64)][kc(40)][g(4)][lane*8+e] ; k = kc*32+8*(l>>4)+e ; s = sb*16+(l&15)
__global__ void wfrag_kernel(const float* __restrict__ Wx, const float* __restrict__ Wh,
                             __hip_bfloat16* __restrict__ wbf) {
    int tid  = blockIdx.x * 256 + threadIdx.x;   // total 64*40*4*64 = 655,360
    int l    = tid & 63;
    int frag = tid >> 6;                         // (sb*40 + kc)*4 + g
    int g    = frag & 3;
    int kc   = (frag >> 2) % 40;
    int sb   = frag / 160;
    int s    = sb * 16 + (l & 15);
    int k0   = kc * 32 + 8 * (l >> 4);
    __hip_bfloat16* dst = wbf + (size_t)frag * 512 + l * 8;
#pragma unroll
    for (int e = 0; e < 8; ++e) {
        int k = k0 + e;
        float v = (k < FB) ? Wx[((size_t)g * FB + k) * SB + s]
                           : Wh[((size_t)g * SB + (k - FB)) * SB + s];
        dst[e] = __float2bfloat16(v);
    }
}

// ---------------- persistent LSTM kernel: 256 single-wave WGs ----------------
// WG b = (m = b>>6, sb = b&63): rows m*16..+16, cols sb*16..+16, ALL 4 gates,
// FULL K=1280. Gates in-register (C-layout col=l&15,row=(l>>4)*4+i): no cross-
// wave reduce, no __syncthreads. h repack via 1KB wave-local LDS; wave writes
// ITS half of fragment [sb>>1][m]: halfwords 256*(sb&1)..+256  <-- r12 bug was
// dropping the (sb&1) offset on the global store (both parities clobbered half 0).
__global__ __launch_bounds__(64, 1) void lstm_persist(
    const __hip_bfloat16* __restrict__ xaf,   // [512][4][8][512]
    const __hip_bfloat16* __restrict__ wbf,   // [64][40][4][512]
    const float* __restrict__ bias,           // [4][1024]
    __hip_bfloat16* __restrict__ hfrag,       // [4][32][4][512]
    float* __restrict__ cbuf,                 // [64][1024] fp32 c-state
    float* __restrict__ out,                  // [512][64][1024]
    unsigned int* __restrict__ flag,          // [512][256] per-wave step flags
    int t0, int nsteps, int use_sync)
{
    __shared__ unsigned long long lds64[128]; // 1KB wave-local repack buffer
    unsigned short* lds16 = (unsigned short*)lds64;
    const int l  = threadIdx.x;               // 0..63
    const int m  = blockIdx.x >> 6;           // m-tile 0..3
    const int sb = blockIdx.x & 63;           // col-block 0..63
    const int c_ = l & 15;                    // col within block (C-layout)
    const int rg = (l >> 4) * 4;              // row group base (C-layout)
    const int sg = sb * 16 + c_;              // global col
    const int k8hi = 2 * (sb & 1) + (c_ >> 3);// dest fragment lane-high bits
    const int half = (sb & 1) * 64;           // this wave's u64 offset in fragment

    const __hip_bfloat16* wp = wbf + (size_t)sb * 81920 + l * 8;  // 160 frags/sb

    // ---- one-time: bias + c-state (4 rows x 1 col per lane)
    float br[4];
#pragma unroll
    for (int g = 0; g < 4; ++g) br[g] = bias[g * SB + sg];
    f32x4 creg;
#pragma unroll
    for (int i = 0; i < 4; ++i) creg[i] = cbuf[(size_t)(m * 16 + rg + i) * SB + sg];

    f32x4 acc[4];
    // ---- prologue: x-part of first step (h-independent)
#pragma unroll
    for (int g = 0; g < 4; ++g) acc[g] = (f32x4){0.f, 0.f, 0.f, 0.f};
    {
        const __hip_bfloat16* xs = xaf + (size_t)t0 * 16384;
#pragma unroll
        for (int kc = 0; kc < 8; ++kc) {
            bf16x8 a = *reinterpret_cast<const bf16x8*>(xs + (size_t)(m * 8 + kc) * 512 + l * 8);
#pragma unroll
            for (int g = 0; g < 4; ++g) {
                bf16x8 w = *reinterpret_cast<const bf16x8*>(wp + (size_t)(kc * 4 + g) * 512);
                acc[g] = MFMA(a, w, acc[g]);
            }
        }
    }

    for (int tt = 0; tt < nsteps; ++tt) {
        const int t = t0 + tt;

        if (use_sync && tt > 0) {
            // license (overwrite of buf[(t+1)&3]): same-m 64 waves done with t-3.
            unsigned lic = 1u;
            const unsigned int* f3 = flag + (size_t)(t - 3) * NWG + m * 64;
            if (tt > 2)
                lic = __hip_atomic_load(&f3[l], __ATOMIC_RELAXED, __HIP_MEMORY_SCOPE_AGENT);
            // critical wait: all 64 same-m producers flagged step t-1
            const unsigned int* f1 = flag + (size_t)(t - 1) * NWG + m * 64;
            for (;;) {
                unsigned a = __hip_atomic_load(&f1[l], __ATOMIC_RELAXED, __HIP_MEMORY_SCOPE_AGENT);
                if (__all(a != 0)) break;
            }
            if (tt > 2) {
                while (!__all(lic != 0))
                    lic = __hip_atomic_load(&f3[l], __ATOMIC_RELAXED, __HIP_MEMORY_SCOPE_AGENT);
            }
            asm volatile("" ::: "memory");    // no load motion across the wait
        }

        // ---- h-part: 32 chunks x 4 gates (sc1 loads batched by compiler)
        const __hip_bfloat16* hs = hfrag + (size_t)(t & 3) * 65536;
#pragma unroll
        for (int kc = 8; kc < 40; ++kc) {
            bf16x8 a = load_frag_dev(hs + (size_t)((kc - 8) * 4 + m) * 512 + l * 8);
#pragma unroll
            for (int g = 0; g < 4; ++g) {
                bf16x8 w = *reinterpret_cast<const bf16x8*>(wp + (size_t)(kc * 4 + g) * 512);
                acc[g] = MFMA(a, w, acc[g]);
            }
        }

        // ---- gates + state update: fully in-register (4 rows x 1 col per lane)
        float hv[4];
#pragma unroll
        for (int i = 0; i < 4; ++i) {
            float zi = acc[0][i] + br[0];
            float zf = acc[1][i] + br[1];
            float zg = acc[2][i] + br[2];
            float zo = acc[3][i] + br[3];
            float ig = 1.f / (1.f + expf(-zi));
            float fg = 1.f / (1.f + expf(-zf));
            float gg = tanhf(zg);
            float og = 1.f / (1.f + expf(-zo));
            float c  = fg * creg[i] + ig * gg;
            hv[i]    = og * tanhf(c);
            creg[i]  = c;
            // scatter into wave-local LDS at fragment halfword position
            lds16[(k8hi * 16 + rg + i) * 8 + (l & 7)] =
                __bfloat16_as_ushort(__float2bfloat16(hv[i]));
        }
        asm volatile("s_waitcnt lgkmcnt(0)" ::: "memory");
        // read back packed u64 and store the wave's 512B half-fragment (sc1)
        {
            unsigned long long pv = lds64[half + l];
            unsigned long long* hd = reinterpret_cast<unsigned long long*>(
                hfrag + (size_t)((t + 1) & 3) * 65536 + (size_t)((sb >> 1) * 4 + m) * 512);
            __hip_atomic_store(&hd[half + l], pv, __ATOMIC_RELAXED, __HIP_MEMORY_SCOPE_AGENT);
        }
        // ---- arrive: drain own stores, lane-0 flag
        if (use_sync) {
            asm volatile("s_waitcnt vmcnt(0)" ::: "memory");
            if (l == 0)
                __hip_atomic_store(&flag[(size_t)t * NWG + blockIdx.x], 1u,
                                   __ATOMIC_RELAXED, __HIP_MEMORY_SCOPE_AGENT);
        }

        // ---- out stores (off the flag path)
#pragma unroll
        for (int i = 0; i < 4; ++i)
            out[(size_t)t * (NB * SB) + (size_t)(m * 16 + rg + i) * SB + sg] = hv[i];

        // ---- tail: x-part of next step (h-independent, hides wait latency)
        if (tt + 1 < nsteps) {
#pragma unroll
            for (int g = 0; g < 4; ++g) acc[g] = (f32x4){0.f, 0.f, 0.f, 0.f};
            const __hip_bfloat16* xs = xaf + (size_t)(t + 1) * 16384;
#pragma unroll
            for (int kc = 0; kc < 8; ++kc) {
                bf16x8 a = *reinterpret_cast<const bf16x8*>(xs + (size_t)(m * 8 + kc) * 512 + l * 8);
#pragma unroll
                for (int g = 0; g < 4; ++g) {
                    bf16x8 w = *reinterpret_cast<const bf16x8*>(wp + (size_t)(kc * 4 + g) * 512);
                    acc[g] = MFMA(a, w, acc[g]);
                }
            }
        }
    }

    // ---- persist c-state (needed for the per-step fallback path)
#pragma unroll
    for (int i = 0; i < 4; ++i) cbuf[(size_t)(m * 16 + rg + i) * SB + sg] = creg[i];
}

extern "C" void kernel_launch(void* const* d_in, const int* in_sizes, int n_in,
                              void* d_out, int out_size, void* d_ws, size_t ws_size,
                              hipStream_t stream) {
    const float* x  = (const float*)d_in[0];   // [512][64][256]
    const float* Wx = (const float*)d_in[1];   // [4][256][1024]
    const float* Wh = (const float*)d_in[2];   // [4][1024][1024]
    const float* b  = (const float*)d_in[3];   // [4][1024]
    float* out = (float*)d_out;                // [512][64][1024]

    char* ws = (char*)d_ws;
    __hip_bfloat16* xaf   = (__hip_bfloat16*)ws;                 // 16,777,216 B
    __hip_bfloat16* wbf   = (__hip_bfloat16*)(ws + 16777216);    // 10,485,760 B
    __hip_bfloat16* hfrag = (__hip_bfloat16*)(ws + 27262976);    //    524,288 B (4 bufs)
    float*          cbuf  = (float*)(ws + 27787264);             //    262,144 B
    unsigned int*   flag  = (unsigned int*)(ws + 28049408);      //    524,288 B

    hipLaunchKernelGGL(xfrag_kernel, dim3(4096), dim3(256), 0, stream, x, xaf);
    hipLaunchKernelGGL(wfrag_kernel, dim3(2560), dim3(256), 0, stream, Wx, Wh, wbf);
    hipMemsetAsync(hfrag, 0, 524288, stream);   // h[-1] = 0
    hipMemsetAsync(cbuf, 0, 262144, stream);    // c[-1] = 0
    hipMemsetAsync(flag, 0, 524288, stream);    // per-step per-wave flags

    const __hip_bfloat16* p_xaf = xaf;
    const __hip_bfloat16* p_wbf = wbf;
    const float* p_bias = b;
    __hip_bfloat16* p_hfrag = hfrag;
    float* p_cbuf = cbuf;
    float* p_out = out;
    unsigned int* p_flag = flag;
    int z0 = 0, ns = T_LEN, us = 1;
    void* args[] = {&p_xaf, &p_wbf, &p_bias, &p_hfrag, &p_cbuf, &p_out, &p_flag, &z0, &ns, &us};
    hipError_t err = hipLaunchCooperativeKernel((void*)lstm_persist, dim3(NWG), dim3(64),
                                                args, 0, stream);
    if (err != hipSuccess) {
        // fallback: per-step plain launches (kernel boundaries order memory)
        for (int t = 0; t < T_LEN; ++t) {
            hipLaunchKernelGGL(lstm_persist, dim3(NWG), dim3(64), 0, stream,
                               xaf, wbf, b, hfrag, cbuf, out, flag, t, 1, 0);
        }
    }
}

// Round 14
// 2324.246 us; speedup vs baseline: 5.1535x; 5.1535x over previous
//
#include <hip/hip_runtime.h>
#include <hip/hip_bf16.h>

#define T_LEN 512
#define NB 64      // batch
#define FB 256     // input features
#define SB 1024    // hidden size
#define NWG 128    // persistent workgroups

typedef __attribute__((ext_vector_type(8))) short bf16x8;
typedef __attribute__((ext_vector_type(4))) float f32x4;
typedef __attribute__((ext_vector_type(2))) float f32x2;

#define MFMA(a, b, c) __builtin_amdgcn_mfma_f32_16x16x32_bf16((a), (b), (c), 0, 0, 0)

// device-scope (sc1) 16B fragment load as 2 relaxed agent u64 atomics
__device__ __forceinline__ bf16x8 load_frag_dev(const __hip_bfloat16* p) {
    const unsigned long long* q = (const unsigned long long*)p;
    unsigned long long a = __hip_atomic_load(q,     __ATOMIC_RELAXED, __HIP_MEMORY_SCOPE_AGENT);
    unsigned long long b = __hip_atomic_load(q + 1, __ATOMIC_RELAXED, __HIP_MEMORY_SCOPE_AGENT);
    union { unsigned long long u[2]; bf16x8 v; } r;
    r.u[0] = a; r.u[1] = b;
    return r.v;
}

// ---------------- prep: x -> MFMA A-fragment order, bf16 ----------------
// XAf[t][m(4)][kc(8)][lane*8+e] ; element = x[t][m*16+(l&15)][kc*32+8*(l>>4)+e]
__global__ void xfrag_kernel(const float* __restrict__ x, __hip_bfloat16* __restrict__ xaf) {
    int tid  = blockIdx.x * 256 + threadIdx.x;   // total T*4*8*64 = 1,048,576
    int l    = tid & 63;
    int frag = tid >> 6;                         // t*32 + m*8 + kc
    int kc   = frag & 7;
    int m    = (frag >> 3) & 3;
    int t    = frag >> 5;
    int row  = m * 16 + (l & 15);
    int k0   = kc * 32 + 8 * (l >> 4);
    const float* src = x + ((size_t)(t * NB + row)) * FB + k0;
    __hip_bfloat16* dst = xaf + (size_t)frag * 512 + l * 8;
#pragma unroll
    for (int e = 0; e < 8; ++e) dst[e] = __float2bfloat16(src[e]);
}

// ------------- prep: [Wx;Wh] -> per-(sb,wave) register-load order -------------
// WBf[sb(64)][wv(4)][kcw(10)][g(4)][lane*8+e]
// kc(wv,kcw) = kcw<2 ? wv*2+kcw : 8 + wv*8 + (kcw-2)   (x-chunks spread over waves)
// k = kc*32+8*(l>>4)+e ; s = sb*16+(l&15)
__global__ void wfrag_kernel(const float* __restrict__ Wx, const float* __restrict__ Wh,
                             __hip_bfloat16* __restrict__ wbf) {
    int tid  = blockIdx.x * 256 + threadIdx.x;   // total 64*4*10*4*64 = 655,360
    int l    = tid & 63;
    int frag = tid >> 6;                         // ((sb*4+wv)*10+kcw)*4+g
    int g    = frag & 3;
    int kcw  = (frag >> 2) % 10;
    int wv   = (frag / 40) & 3;
    int sb   = frag / 160;
    int kc   = (kcw < 2) ? (wv * 2 + kcw) : (8 + wv * 8 + (kcw - 2));
    int s    = sb * 16 + (l & 15);
    int k0   = kc * 32 + 8 * (l >> 4);
    __hip_bfloat16* dst = wbf + (size_t)frag * 512 + l * 8;
#pragma unroll
    for (int e = 0; e < 8; ++e) {
        int k = k0 + e;
        float v = (k < FB) ? Wx[((size_t)g * FB + k) * SB + s]
                           : Wh[((size_t)g * SB + (k - FB)) * SB + s];
        dst[e] = __float2bfloat16(v);
    }
}

// ---------------- persistent LSTM kernel ----------------
// r11 structure (2340 us), ONE delta: 28 of each wave's 40 weight fragments
// (i=12..39, the last 7 h-chunks x 4 gates) are copied ONCE into wave-local
// LDS and read via ds_read_b128 in the K-loop. r9 proved the compiler keeps
// re-streaming weights from L2 every step (VGPR=152, ~160KB/CU/step at
// ~135-270 GB/s per-CU L2 BW = 0.6-1.2us of the 4.57us step). Wave-local ->
// no barrier needed; l*16 ds_read pattern is conflict-free.
__global__ __launch_bounds__(256, 1) void lstm_persist(
    const __hip_bfloat16* __restrict__ xaf,   // [512][4][8][512]
    const __hip_bfloat16* __restrict__ wbf,   // [64][4][10][4][512]
    const float* __restrict__ bias,           // [4][1024]
    __hip_bfloat16* __restrict__ hfrag,       // [4][32][4][512]
    float* __restrict__ cbuf,                 // [64][1024] fp32 c-state
    float* __restrict__ out,                  // [512][64][1024]
    unsigned int* __restrict__ flag,          // [512][128][4] (16B-padded per-WG flags)
    int t0, int nsteps, int use_sync)
{
    __shared__ float part[4 * 32 * 4 * 17];               // 34,816 B
    __shared__ __align__(16) unsigned char wlds[114688];  // 112 KB: 4 waves x 28 frags x 1KB
    const int tid = threadIdx.x;
    const int wv  = tid >> 6;
    const int l   = tid & 63;
    const int nh  = blockIdx.x >> 6;
    const int sb  = blockIdx.x & 63;
    const int lr  = l & 15;
    const int lg  = l >> 4;
    const int m0  = nh * 2, m1 = nh * 2 + 1;

    // my wave's 16 producer WGs: same nh, sb' = wv*16 .. wv*16+15
    const int pidx = nh * 64 + wv * 16 + (l & 15);

    // gate-phase element mapping: thread -> (row gn, 2 consecutive s-cols)
    const int gn  = tid >> 3;                 // 0..31 local row
    const int sc0 = (tid & 7) * 2;            // 0,2,..,14

    // ---- one-time: weight fragments. i=0..11 kept as loads (L2-resident);
    //      i=12..39 copied into wave-local LDS (no barrier: same-wave r/w).
    const __hip_bfloat16* wp = wbf + ((size_t)(sb * 4 + wv) * 40) * 512 + l * 8;
    unsigned char* wl = wlds + (size_t)wv * 28672 + (size_t)l * 16;
#pragma unroll
    for (int i = 12; i < 40; ++i)
        *reinterpret_cast<uint4*>(wl + (size_t)(i - 12) * 1024) =
            *reinterpret_cast<const uint4*>(wp + (size_t)i * 512);
    bf16x8 wf[12];
#pragma unroll
    for (int i = 0; i < 12; ++i) wf[i] = *reinterpret_cast<const bf16x8*>(wp + (size_t)i * 512);

    // ---- one-time: bias + c-state for this thread's (gn, sc0..sc0+1)
    float br[8];
#pragma unroll
    for (int g = 0; g < 4; ++g) {
        br[g * 2]     = bias[g * SB + sb * 16 + sc0];
        br[g * 2 + 1] = bias[g * SB + sb * 16 + sc0 + 1];
    }
    f32x2 creg = *reinterpret_cast<const f32x2*>(
        &cbuf[(nh * 32 + gn) * SB + sb * 16 + sc0]);

    f32x4 acc[2][4];
    // ---- prologue: x-part of first step (h-independent)
#pragma unroll
    for (int mi = 0; mi < 2; ++mi)
#pragma unroll
        for (int g = 0; g < 4; ++g) acc[mi][g] = (f32x4){0.f, 0.f, 0.f, 0.f};
    {
        const __hip_bfloat16* xs = xaf + (size_t)t0 * 16384;
#pragma unroll
        for (int j = 0; j < 2; ++j) {
            int kc = wv * 2 + j;
            bf16x8 a0 = *reinterpret_cast<const bf16x8*>(xs + (size_t)(m0 * 8 + kc) * 512 + l * 8);
            bf16x8 a1 = *reinterpret_cast<const bf16x8*>(xs + (size_t)(m1 * 8 + kc) * 512 + l * 8);
#pragma unroll
            for (int g = 0; g < 4; ++g) {
                acc[0][g] = MFMA(a0, wf[j * 4 + g], acc[0][g]);
                acc[1][g] = MFMA(a1, wf[j * 4 + g], acc[1][g]);
            }
        }
    }

    for (int tt = 0; tt < nsteps; ++tt) {
        const int t = t0 + tt;

        if (use_sync && tt > 0) {
            // license (overwrite of buf[(t+1)&3]): same-nh 64 WGs done with t-3.
            // Issue the load BEFORE the critical poll; evaluate after (overlapped).
            unsigned lic = 1u;
            const unsigned int* f3 = flag + (size_t)(t - 3) * 512;
            if (tt > 2)
                lic = __hip_atomic_load(&f3[(nh * 64 + l) * 4], __ATOMIC_RELAXED, __HIP_MEMORY_SCOPE_AGENT);
            // critical wait: my 16 producers arrived at t-1 (h[t] cols ready)
            const unsigned int* f1 = flag + (size_t)(t - 1) * 512;
            for (;;) {
                unsigned a = __hip_atomic_load(&f1[pidx * 4], __ATOMIC_RELAXED, __HIP_MEMORY_SCOPE_AGENT);
                if (__all(a != 0)) break;
            }
            // evaluate license (t-3 is ~2 steps stale: first-pass success typical)
            if (tt > 2) {
                while (!__all(lic != 0))
                    lic = __hip_atomic_load(&f3[(nh * 64 + l) * 4], __ATOMIC_RELAXED, __HIP_MEMORY_SCOPE_AGENT);
            }
            asm volatile("" ::: "memory");   // no load motion across the wait
        }

        // ---- h-part MFMAs (sc1 h loads batched by compiler; weights from LDS)
        const __hip_bfloat16* hs = hfrag + (size_t)(t & 3) * 65536;
#pragma unroll
        for (int j = 0; j < 8; ++j) {
            int kch = wv * 8 + j;
            bf16x8 a0 = load_frag_dev(hs + (size_t)(kch * 4 + m0) * 512 + l * 8);
            bf16x8 a1 = load_frag_dev(hs + (size_t)(kch * 4 + m1) * 512 + l * 8);
#pragma unroll
            for (int g = 0; g < 4; ++g) {
                const int i = (2 + j) * 4 + g;
                bf16x8 w;
                if (i < 12) w = wf[i];
                else        w = *reinterpret_cast<const bf16x8*>(wl + (size_t)(i - 12) * 1024);
                acc[0][g] = MFMA(a0, w, acc[0][g]);
                acc[1][g] = MFMA(a1, w, acc[1][g]);
            }
        }

        // ---- cross-wave K-reduce via LDS
#pragma unroll
        for (int mi = 0; mi < 2; ++mi)
#pragma unroll
            for (int g = 0; g < 4; ++g)
#pragma unroll
                for (int i = 0; i < 4; ++i)
                    part[((wv * 32 + mi * 16 + lg * 4 + i) * 4 + g) * 17 + lr] = acc[mi][g][i];
        __syncthreads();

        // ---- gates + state update: (gn, sc0..sc0+1) per thread
        {
            float z[4][2];
#pragma unroll
            for (int g = 0; g < 4; ++g) {
                float s0 = 0.f, s1 = 0.f;
#pragma unroll
                for (int w2 = 0; w2 < 4; ++w2) {
                    const float* pr = &part[((w2 * 32 + gn) * 4 + g) * 17 + sc0];
                    s0 += pr[0];
                    s1 += pr[1];
                }
                z[g][0] = s0 + br[g * 2];
                z[g][1] = s1 + br[g * 2 + 1];
            }
            float hv[2];
#pragma unroll
            for (int e = 0; e < 2; ++e) {
                float ig = 1.f / (1.f + expf(-z[0][e]));
                float fg = 1.f / (1.f + expf(-z[1][e]));
                float gg = tanhf(z[2][e]);
                float og = 1.f / (1.f + expf(-z[3][e]));
                float c  = fg * creg[e] + ig * gg;
                hv[e]    = og * tanhf(c);
                creg[e]  = c;
            }
            int ng  = nh * 32 + gn;
            int sg0 = sb * 16 + sc0;
            // out: one float2 store (plain cached; flushed at kernel end)
            *reinterpret_cast<f32x2*>(&out[(size_t)t * (NB * SB) + (size_t)ng * SB + sg0])
                = (f32x2){hv[0], hv[1]};
            // h-frag: one device-scope u32 store (2 packed bf16)
            unsigned u0 = (unsigned)__bfloat16_as_ushort(__float2bfloat16(hv[0]));
            unsigned u1 = (unsigned)__bfloat16_as_ushort(__float2bfloat16(hv[1]));
            int kch  = sg0 >> 5;
            int k8   = sg0 & 31;
            int lane = (k8 >> 3) * 16 + (ng & 15);
            unsigned int* hd = reinterpret_cast<unsigned int*>(
                hfrag + (size_t)((t + 1) & 3) * 65536
                + (size_t)(kch * 4 + (ng >> 4)) * 512 + lane * 8 + (k8 & 7));
            __hip_atomic_store(hd, u0 | (u1 << 16), __ATOMIC_RELAXED, __HIP_MEMORY_SCOPE_AGENT);
        }

        // ---- arrive: syncthreads drains all threads' sc1 stores, then flag
        if (use_sync) {
            __syncthreads();
            if (tid == 0)
                __hip_atomic_store(&flag[((size_t)t * 128 + blockIdx.x) * 4], 1u,
                                   __ATOMIC_RELAXED, __HIP_MEMORY_SCOPE_AGENT);
        }

        // ---- tail: x-part of next step (h-independent, hides wait latency)
        if (tt + 1 < nsteps) {
#pragma unroll
            for (int mi = 0; mi < 2; ++mi)
#pragma unroll
                for (int g = 0; g < 4; ++g) acc[mi][g] = (f32x4){0.f, 0.f, 0.f, 0.f};
            const __hip_bfloat16* xs = xaf + (size_t)(t + 1) * 16384;
#pragma unroll
            for (int j = 0; j < 2; ++j) {
                int kc = wv * 2 + j;
                bf16x8 a0 = *reinterpret_cast<const bf16x8*>(xs + (size_t)(m0 * 8 + kc) * 512 + l * 8);
                bf16x8 a1 = *reinterpret_cast<const bf16x8*>(xs + (size_t)(m1 * 8 + kc) * 512 + l * 8);
#pragma unroll
                for (int g = 0; g < 4; ++g) {
                    acc[0][g] = MFMA(a0, wf[j * 4 + g], acc[0][g]);
                    acc[1][g] = MFMA(a1, wf[j * 4 + g], acc[1][g]);
                }
            }
        }
    }

    // ---- persist c-state (needed for the per-step fallback path)
    *reinterpret_cast<f32x2*>(&cbuf[(nh * 32 + gn) * SB + sb * 16 + sc0]) = creg;
}

extern "C" void kernel_launch(void* const* d_in, const int* in_sizes, int n_in,
                              void* d_out, int out_size, void* d_ws, size_t ws_size,
                              hipStream_t stream) {
    const float* x  = (const float*)d_in[0];   // [512][64][256]
    const float* Wx = (const float*)d_in[1];   // [4][256][1024]
    const float* Wh = (const float*)d_in[2];   // [4][1024][1024]
    const float* b  = (const float*)d_in[3];   // [4][1024]
    float* out = (float*)d_out;                // [512][64][1024]

    char* ws = (char*)d_ws;
    __hip_bfloat16* xaf   = (__hip_bfloat16*)ws;                 // 16,777,216 B
    __hip_bfloat16* wbf   = (__hip_bfloat16*)(ws + 16777216);    // 10,485,760 B
    __hip_bfloat16* hfrag = (__hip_bfloat16*)(ws + 27262976);    //    524,288 B (4 bufs)
    float*          cbuf  = (float*)(ws + 27787264);             //    262,144 B
    unsigned int*   flag  = (unsigned int*)(ws + 28049408);      //  1,048,576 B

    hipLaunchKernelGGL(xfrag_kernel, dim3(4096), dim3(256), 0, stream, x, xaf);
    hipLaunchKernelGGL(wfrag_kernel, dim3(2560), dim3(256), 0, stream, Wx, Wh, wbf);
    hipMemsetAsync(hfrag, 0, 524288, stream);   // h[-1] = 0
    hipMemsetAsync(cbuf, 0, 262144, stream);    // c[-1] = 0
    hipMemsetAsync(flag, 0, 1048576, stream);   // per-step per-WG flags

    const __hip_bfloat16* p_xaf = xaf;
    const __hip_bfloat16* p_wbf = wbf;
    const float* p_bias = b;
    __hip_bfloat16* p_hfrag = hfrag;
    float* p_cbuf = cbuf;
    float* p_out = out;
    unsigned int* p_flag = flag;
    int z0 = 0, ns = T_LEN, us = 1;
    void* args[] = {&p_xaf, &p_wbf, &p_bias, &p_hfrag, &p_cbuf, &p_out, &p_flag, &z0, &ns, &us};
    hipError_t err = hipLaunchCooperativeKernel((void*)lstm_persist, dim3(NWG), dim3(256),
                                                args, 0, stream);
    if (err != hipSuccess) {
        // fallback: per-step plain launches (kernel boundaries order memory)
        for (int t = 0; t < T_LEN; ++t) {
            hipLaunchKernelGGL(lstm_persist, dim3(NWG), dim3(256), 0, stream,
                               xaf, wbf, b, hfrag, cbuf, out, flag, t, 1, 0);
        }
    }
}